// Round 1
// baseline (409.088 us; speedup 1.0000x reference)
//
#include <hip/hip_runtime.h>
#include <hip/hip_bf16.h>

// Problem dims (compile-time constants, match reference)
constexpr int B  = 8;
constexpr int A  = 6;     // agents: both query count and key count
constexpr int QS = 32;
constexpr int KS = 1024;
constexpr int C  = 256;
constexpr int H  = 64;
constexpr int W_ = 64;
constexpr long CHW  = (long)C * H * W_;        // 1,048,576 floats per (b,k) plane
constexpr long CHW4 = CHW / 4;                  // 262,144 float4s
constexpr int  BLOCKS_PER_B = (int)(CHW4 / 256); // 1024 blocks of 256 threads per batch

// ---------------------------------------------------------------------------
// Kernel 1: tiny attention head. One block per batch b.
//   query[q][d] = sum_s qu[b,q,s] * W[d,s] + bias[d]          (6 x 1024)
//   attn[k][q]  = sum_d k[b,k,d] * query[q][d]                (6 x 6)
//   attn_sm     = softmax over k (axis=1)                     (6 x 6)
// Writes attn_sm to the d_out tail in [b][k][q] order (reference output #1).
// ---------------------------------------------------------------------------
__global__ __launch_bounds__(256) void attn_kernel(
    const float* __restrict__ qu,    // [B,A,QS]
    const float* __restrict__ kmat,  // [B,A,KS]
    const float* __restrict__ Wm,    // [KS,QS]
    const float* __restrict__ bias,  // [KS]
    float* __restrict__ attn_out)    // [B,A,A]  (b,k,q)
{
    __shared__ float s_qu[A * QS];
    __shared__ float s_query[A][KS];
    __shared__ float s_attn[A][A];   // [k][q]

    const int b   = blockIdx.x;
    const int tid = threadIdx.x;

    // stage qu[b]
    for (int i = tid; i < A * QS; i += 256) s_qu[i] = qu[b * A * QS + i];
    __syncthreads();

    // query projection: 6144 entries, each a K=32 dot
    for (int i = tid; i < A * KS; i += 256) {
        const int q = i >> 10;          // i / 1024
        const int d = i & (KS - 1);     // i % 1024
        float acc = bias[d];
        const float* wrow = Wm + d * QS;
        const float* qrow = s_qu + q * QS;
        #pragma unroll
        for (int s = 0; s < QS; ++s) acc += qrow[s] * wrow[s];
        s_query[q][d] = acc;
    }
    __syncthreads();

    // 36 scores; 4 waves, 9 pairs each; 1024-dot split across 64 lanes
    const int wave = tid >> 6;
    const int lane = tid & 63;
    for (int p = wave; p < A * A; p += 4) {
        const int kk = p / A;
        const int q  = p % A;
        const float* krow = kmat + ((long)b * A + kk) * KS;
        float partial = 0.f;
        for (int d = lane; d < KS; d += 64) partial += krow[d] * s_query[q][d];
        #pragma unroll
        for (int off = 32; off > 0; off >>= 1)
            partial += __shfl_down(partial, off, 64);
        if (lane == 0) s_attn[kk][q] = partial;
    }
    __syncthreads();

    // softmax over k for each q (6 lanes do the 6 columns)
    if (tid < A) {
        const int q = tid;
        float m = s_attn[0][q];
        #pragma unroll
        for (int kk = 1; kk < A; ++kk) m = fmaxf(m, s_attn[kk][q]);
        float e[A];
        float sum = 0.f;
        #pragma unroll
        for (int kk = 0; kk < A; ++kk) { e[kk] = expf(s_attn[kk][q] - m); sum += e[kk]; }
        const float inv = 1.f / sum;
        #pragma unroll
        for (int kk = 0; kk < A; ++kk)
            attn_out[b * A * A + kk * A + q] = e[kk] * inv;
    }
}

// ---------------------------------------------------------------------------
// Kernel 2: weighted combine. out[b,q,chw] = sum_k attn[b,k,q] * v[b,k,chw].
// Each thread: 6 float4 loads (one per k-plane), 6 float4 stores (one per
// q-plane). Reads v exactly once, writes out exactly once -> HBM-minimal.
// ---------------------------------------------------------------------------
__global__ __launch_bounds__(256) void combine_kernel(
    const float* __restrict__ v,     // [B,A,C,H,W]
    const float* __restrict__ attn,  // [B,A,A]  (b,k,q)
    float* __restrict__ out)         // [B,A,C,H,W] (b,q,...)
{
    __shared__ float s_a[A * A];

    const int b   = blockIdx.x >> 10;         // / BLOCKS_PER_B
    const int blk = blockIdx.x & (BLOCKS_PER_B - 1);

    if (threadIdx.x < A * A) s_a[threadIdx.x] = attn[b * A * A + threadIdx.x];
    __syncthreads();

    const long i4   = (long)blk * 256 + threadIdx.x;   // float4 index in plane
    const long base = (long)b * A * CHW4 + i4;
    const float4* vb = reinterpret_cast<const float4*>(v)   + base;
    float4*       ob = reinterpret_cast<float4*>(out)       + base;

    float4 vv[A];
    #pragma unroll
    for (int kk = 0; kk < A; ++kk) vv[kk] = vb[(long)kk * CHW4];

    #pragma unroll
    for (int q = 0; q < A; ++q) {
        float4 acc = make_float4(0.f, 0.f, 0.f, 0.f);
        #pragma unroll
        for (int kk = 0; kk < A; ++kk) {
            const float a = s_a[kk * A + q];
            acc.x += a * vv[kk].x;
            acc.y += a * vv[kk].y;
            acc.z += a * vv[kk].z;
            acc.w += a * vv[kk].w;
        }
        ob[(long)q * CHW4] = acc;
    }
}

extern "C" void kernel_launch(void* const* d_in, const int* in_sizes, int n_in,
                              void* d_out, int out_size, void* d_ws, size_t ws_size,
                              hipStream_t stream) {
    const float* qu   = (const float*)d_in[0];
    const float* kmat = (const float*)d_in[1];
    const float* v    = (const float*)d_in[2];
    const float* Wm   = (const float*)d_in[3];
    const float* bias = (const float*)d_in[4];

    float* out      = (float*)d_out;
    float* attn_out = out + (long)B * A * CHW;   // tuple output #1 lives after out

    attn_kernel<<<B, 256, 0, stream>>>(qu, kmat, Wm, bias, attn_out);
    combine_kernel<<<B * BLOCKS_PER_B, 256, 0, stream>>>(v, attn_out, out);
}